// Round 6
// baseline (933.088 us; speedup 1.0000x reference)
//
#include <hip/hip_runtime.h>
#include <stdint.h>

#define DI __device__ __forceinline__

constexpr int Bn = 32, Cc = 64, Wn = 96, Hn = 96, Ln = 32, NG = 128, OUTC = 256;
constexpr int SEQ = 96;
constexpr long long NPIX = (long long)Bn * Wn * Hn;   // 294912
constexpr int GRAM_BLOCKS = 128;
constexpr int PIX_PER_BLOCK = (int)(NPIX / GRAM_BLOCKS); // 2304

typedef __attribute__((ext_vector_type(8))) short bf16x8;
typedef __attribute__((ext_vector_type(4))) float f32x4;

DI float tanhf_(float x) { return 1.0f - 2.0f / (__expf(2.0f * x) + 1.0f); } // NaN-free both tails
DI float bf2f(unsigned short u) { return __uint_as_float(((unsigned)u) << 16); }
DI unsigned short f2bf(float f) {
    unsigned u = __float_as_uint(f);
    u += 0x7FFFu + ((u >> 16) & 1u);   // RNE
    return (unsigned short)(u >> 16);
}

// ---------------------------------------------------------------------------
// Input-projection GEMM via MFMA. One block per chain (b,q); A = 96x64 tile.
// OUTPUT LAYOUT (R5 change): xg[chain][gate o][t]  (gate-major!) so that the
// recurrent kernel's per-lane stream is 96 contiguous bf16 = 12x16B chunks.
// R5 counters: with [t][o] layout lstm_rec had 256B/wave outstanding ->
// 600 GB/s latency-bound, 4200 cyc/step. Gate-major enables 16B x 8-step
// chunked prefetch.
// TRANSPOSE=1: input x f32 [B,C,W,H], q=w, t=h (transpose in staging).
// TRANSPOSE=0: input v bf16 [B,H,W,64], q=h, t=w (contiguous slab).
// ---------------------------------------------------------------------------
template<int TRANSPOSE>
__global__ __launch_bounds__(512, 4)
void xg_kernel(const void* __restrict__ in_,
               const float* __restrict__ wih_f, const float* __restrict__ bih_f,
               const float* __restrict__ bhh_f,
               const float* __restrict__ wih_b, const float* __restrict__ bih_b,
               const float* __restrict__ bhh_b,
               unsigned short* __restrict__ xg)
{
    __shared__ alignas(16) unsigned char AsB[96 * 128];    // bf16 A, swizzled
    __shared__ alignas(16) unsigned char WtB[256 * 128];   // bf16 W^T, swizzled
    __shared__ float biasS[256];

    const int tid = threadIdx.x;
    const int b = blockIdx.x / 96, q = blockIdx.x % 96;

    if (tid < 256) {
        int o = tid, g = o & 127;
        biasS[o] = (o < 128) ? (bih_f[g] + bhh_f[g]) : (bih_b[g] + bhh_b[g]);
    }
    for (int i4 = tid; i4 < 4096; i4 += 512) {
        int wrow = i4 >> 4, k4 = i4 & 15;
        const float* wsrc = (wrow < 128 ? wih_f : wih_b) + (size_t)(wrow & 127) * 64 + k4 * 4;
        float4 v = *(const float4*)wsrc;
        ushort4 p; p.x = f2bf(v.x); p.y = f2bf(v.y); p.z = f2bf(v.z); p.w = f2bf(v.w);
        *(ushort4*)(WtB + wrow * 128 + ((k4 * 8) ^ ((wrow & 7) << 4))) = p;
    }
    if (TRANSPOSE) {
        const float* in = (const float*)in_;
        for (int i = tid; i < 1536; i += 512) {
            int c = i / 24, h4 = i - c * 24;
            float4 v = *(const float4*)(in + (((size_t)b * 64 + c) * 96 + q) * 96 + 4 * h4);
            int r0 = 4 * h4;
            float vv[4] = {v.x, v.y, v.z, v.w};
#pragma unroll
            for (int j = 0; j < 4; ++j) {
                int row = r0 + j;
                *(unsigned short*)(AsB + row * 128 + ((c * 2) ^ ((row & 7) << 4))) = f2bf(vv[j]);
            }
        }
    } else {
        const unsigned short* src = (const unsigned short*)in_ + (size_t)blockIdx.x * 6144;
        for (int i8 = tid; i8 < 768; i8 += 512) {
            int row = i8 >> 3, k8 = i8 & 7;
            bf16x8 p = *(const bf16x8*)(src + (size_t)i8 * 8);
            *(bf16x8*)(AsB + row * 128 + ((k8 * 16) ^ ((row & 7) << 4))) = p;
        }
    }
    __syncthreads();

    const int wv = tid >> 6, lane = tid & 63;
    const int mbase = (wv >> 2) * 48;
    const int nbase = (wv & 3) * 64;
    const int lrow = lane & 15, lk = (lane >> 4) * 8;

    f32x4 acc[3][4];
#pragma unroll
    for (int m = 0; m < 3; ++m)
#pragma unroll
        for (int n = 0; n < 4; ++n)
            acc[m][n] = (f32x4){0.f, 0.f, 0.f, 0.f};

#pragma unroll
    for (int ks = 0; ks < 2; ++ks) {
        const int kb = (ks * 32 + lk) * 2;
        bf16x8 am[3], bn[4];
#pragma unroll
        for (int m = 0; m < 3; ++m) {
            int row = mbase + m * 16 + lrow;
            am[m] = *(const bf16x8*)(AsB + row * 128 + (kb ^ ((row & 7) << 4)));
        }
#pragma unroll
        for (int n = 0; n < 4; ++n) {
            int o = nbase + n * 16 + lrow;
            bn[n] = *(const bf16x8*)(WtB + o * 128 + (kb ^ ((o & 7) << 4)));
        }
#pragma unroll
        for (int m = 0; m < 3; ++m)
#pragma unroll
            for (int n = 0; n < 4; ++n)
                acc[m][n] = __builtin_amdgcn_mfma_f32_16x16x32_bf16(am[m], bn[n], acc[m][n], 0, 0, 0);
    }

    // write [o][t]: per lane 4 consecutive t -> 8B ushort4, 8B-aligned
    unsigned short* ob = xg + (size_t)blockIdx.x * (96 * 256);
#pragma unroll
    for (int n = 0; n < 4; ++n) {
        const int o = nbase + n * 16 + lrow;
        const float bv = biasS[o];
#pragma unroll
        for (int m = 0; m < 3; ++m) {
            const int t0 = mbase + m * 16 + (lane >> 4) * 4;
            ushort4 p;
            p.x = f2bf(acc[m][n][0] + bv);
            p.y = f2bf(acc[m][n][1] + bv);
            p.z = f2bf(acc[m][n][2] + bv);
            p.w = f2bf(acc[m][n][3] + bv);
            *(ushort4*)(ob + (size_t)o * 96 + t0) = p;
        }
    }
}

// ---------------------------------------------------------------------------
// Recurrent-only BiLSTM, one WAVE per (chain, dir), barrier-free.
// Lane owns gates gA=lane (i|f), gB=64+lane (g|o). xg gate-major: lane's two
// streams are contiguous 192B = 12 x bf16x8; chunk loop with 2-chunk (16-step)
// prefetch pipeline -> HBM latency hidden under ~2000 cycles of compute.
// Output bf16 both passes (v was rounded to bf16 downstream anyway).
// ---------------------------------------------------------------------------
#define LSTM_STEP(EL, TE)                                                      \
    {                                                                          \
        const float xA = bf2f((unsigned short)fA[EL]);                         \
        const float xB = bf2f((unsigned short)fB[EL]);                         \
        float aA0 = xA, aA1 = 0.f, aB0 = xB, aB1 = 0.f;                        \
        _Pragma("unroll")                                                      \
        for (int j = 0; j < 32; j += 2) {                                      \
            const float h0 = __shfl(hval, j);                                  \
            const float h1 = __shfl(hval, j + 1);                              \
            aA0 = fmaf(whA[j], h0, aA0);                                       \
            aB0 = fmaf(whB[j], h0, aB0);                                       \
            aA1 = fmaf(whA[j + 1], h1, aA1);                                   \
            aB1 = fmaf(whB[j + 1], h1, aB1);                                   \
        }                                                                      \
        const float aA = aA0 + aA1, aB = aB0 + aB1;                            \
        const float actA = 1.f / (1.f + __expf(-aA));                          \
        const float eB = 1.f / (1.f + __expf(-scB * aB));                      \
        const float actB = fmaf(eB, maB, baB);                                 \
        const float fo = __shfl_xor(actA, 32);                                 \
        const float oo = __shfl_xor(actB, 32);                                 \
        cst = fmaf(fo, cst, actA * actB);                                      \
        const float hnew = oo * tanhf_(cst);                                   \
        hval = hnew;                                                           \
        if (lane < 32) {                                                       \
            const size_t oidx = VERT                                           \
                ? ((((size_t)b * 96 + (TE)) * 96 + q) * 64 + dir * 32 + lane)  \
                : ((((size_t)b * 96 + q) * 96 + (TE)) * 64 + dir * 32 + lane); \
            outU[oidx] = f2bf(hnew);                                           \
        }                                                                      \
    }

template<int VERT>
__global__ __launch_bounds__(256, 4)
void lstm_rec(const unsigned short* __restrict__ xg,
              const float* __restrict__ whh_f, const float* __restrict__ whh_b,
              unsigned short* __restrict__ outU)
{
    const int tid = threadIdx.x;
    const int wv = tid >> 6, lane = tid & 63;
    const int unit = blockIdx.x * 4 + wv;      // [0, 6144)
    const int chain = unit >> 1, dir = unit & 1;
    const int b = chain / 96, q = chain % 96;

    const float* whh = dir ? whh_b : whh_f;
    float whA[32], whB[32];
    {
        const float4* pa = (const float4*)(whh + (size_t)lane * 32);
        const float4* pb = (const float4*)(whh + (size_t)(lane + 64) * 32);
#pragma unroll
        for (int k = 0; k < 8; ++k) {
            float4 a = pa[k], v = pb[k];
            whA[4 * k + 0] = a.x; whA[4 * k + 1] = a.y; whA[4 * k + 2] = a.z; whA[4 * k + 3] = a.w;
            whB[4 * k + 0] = v.x; whB[4 * k + 1] = v.y; whB[4 * k + 2] = v.z; whB[4 * k + 3] = v.w;
        }
    }
    // B-gate activation: lanes<32 = g (tanh = 2*sigm(2x)-1), >=32 = o (sigm)
    const bool istB = (lane < 32);
    const float scB = istB ? 2.f : 1.f, maB = istB ? 2.f : 1.f, baB = istB ? -1.f : 0.f;

    // gate-major streams: 12 x 16B chunks each, 16B-aligned (192B stride)
    const bf16x8* sA = (const bf16x8*)(xg + (size_t)chain * 24576 + (size_t)(dir * 128 + lane) * 96);
    const bf16x8* sB = (const bf16x8*)(xg + (size_t)chain * 24576 + (size_t)(dir * 128 + 64 + lane) * 96);

    bf16x8 curA = sA[dir ? 11 : 0], curB = sB[dir ? 11 : 0];
    bf16x8 nxtA = sA[dir ? 10 : 1], nxtB = sB[dir ? 10 : 1];

    float hval = 0.f, cst = 0.f;

    for (int c = 0; c < 12; ++c) {
        const bf16x8 fA = curA, fB = curB;
        bf16x8 farA = curA, farB = curB;
        if (c < 10) {
            const int cc = dir ? 9 - c : c + 2;
            farA = sA[cc]; farB = sB[cc];
        }
        const int tbase = (dir ? 11 - c : c) * 8;
        if (dir == 0) {
#pragma unroll
            for (int u = 0; u < 8; ++u) LSTM_STEP(u, tbase + u)
        } else {
#pragma unroll
            for (int u = 0; u < 8; ++u) LSTM_STEP(7 - u, tbase + 7 - u)
        }
        curA = nxtA; curB = nxtB;
        nxtA = farA; nxtB = farB;
    }
}

// ---------------------------------------------------------------------------
// Partial Gram (64x64) + channel-sum (64) of hh over this block's pixel chunk.
// ---------------------------------------------------------------------------
__global__ __launch_bounds__(256)
void gram_partial(const unsigned short* __restrict__ hh, float* __restrict__ part)
{
    __shared__ float xs[64][64];
    __shared__ float red[4160];
    const int tid = threadIdx.x;
    for (int e = tid; e < 4160; e += 256) red[e] = 0.0f;
    const int lane = tid & 63, wv = tid >> 6;
    const int li = lane >> 3, lj = lane & 7;
    float acc[8][8]; float macc[8];
#pragma unroll
    for (int i = 0; i < 8; ++i) {
        macc[i] = 0.f;
#pragma unroll
        for (int j = 0; j < 8; ++j) acc[i][j] = 0.f;
    }
    const size_t pix0 = (size_t)blockIdx.x * PIX_PER_BLOCK;
    for (int tile = 0; tile < PIX_PER_BLOCK / 64; ++tile) {
        __syncthreads();
        const unsigned short* src = hh + (pix0 + tile * 64) * 64;
#pragma unroll
        for (int r = 0; r < 4; ++r) {
            int idx4 = tid + 256 * r;
            ushort4 v = ((const ushort4*)src)[idx4];
            int fi = idx4 * 4; int px = fi >> 6; int c = fi & 63;
            xs[px][c] = bf2f(v.x); xs[px][c + 1] = bf2f(v.y);
            xs[px][c + 2] = bf2f(v.z); xs[px][c + 3] = bf2f(v.w);
        }
        __syncthreads();
        for (int p = wv * 16; p < wv * 16 + 16; ++p) {
            float4 ra = *(const float4*)&xs[p][8 * li];
            float4 rb = *(const float4*)&xs[p][8 * li + 4];
            float4 ca = *(const float4*)&xs[p][8 * lj];
            float4 cb = *(const float4*)&xs[p][8 * lj + 4];
            float r[8] = {ra.x, ra.y, ra.z, ra.w, rb.x, rb.y, rb.z, rb.w};
            float cl[8] = {ca.x, ca.y, ca.z, ca.w, cb.x, cb.y, cb.z, cb.w};
#pragma unroll
            for (int i = 0; i < 8; ++i) {
#pragma unroll
                for (int j = 0; j < 8; ++j) acc[i][j] = fmaf(r[i], cl[j], acc[i][j]);
            }
            if (lj == 0) {
#pragma unroll
                for (int i = 0; i < 8; ++i) macc[i] += r[i];
            }
        }
    }
    __syncthreads();
#pragma unroll
    for (int i = 0; i < 8; ++i)
#pragma unroll
        for (int j = 0; j < 8; ++j)
            atomicAdd(&red[(8 * li + i) * 64 + 8 * lj + j], acc[i][j]);
    if (lj == 0)
        for (int i = 0; i < 8; ++i) atomicAdd(&red[4096 + 8 * li + i], macc[i]);
    __syncthreads();
    for (int e = tid; e < 4160; e += 256) part[(size_t)blockIdx.x * 4160 + e] = red[e];
}

__global__ void gram_reduce(const float* __restrict__ part, float* __restrict__ M)
{
    int e = blockIdx.x * 256 + threadIdx.x;
    if (e >= 4160) return;
    double s = 0.0;
    for (int p = 0; p < GRAM_BLOCKS; ++p) s += (double)part[(size_t)p * 4160 + e];
    M[e] = (float)s;
}

// Per-output-channel affine coefficients A,B such that out = A*(w_o . u) + B.
// Weights rounded through bf16 so A/B match the bf16-MFMA conv exactly.
__global__ __launch_bounds__(256)
void stats_kernel(const float* __restrict__ M, const float* __restrict__ cw,
                  const float* __restrict__ cb, const float* __restrict__ bg,
                  const float* __restrict__ bb,
                  float* __restrict__ Aout, float* __restrict__ Bout)
{
    __shared__ float Ml[4160];
    const int tid = threadIdx.x;
    for (int e = tid; e < 4160; e += 256) Ml[e] = M[e];
    __syncthreads();
    float wr[64];
#pragma unroll
    for (int c = 0; c < 64; ++c) wr[c] = bf2f(f2bf(cw[tid * 64 + c]));
    float s1 = 0.f;
#pragma unroll
    for (int c = 0; c < 64; ++c) s1 = fmaf(wr[c], Ml[4096 + c], s1);
    float s2 = 0.f;
    for (int c = 0; c < 64; ++c) {
        const float* Mr = &Ml[c * 64];
        float t = 0.f;
#pragma unroll
        for (int d = 0; d < 64; ++d) t = fmaf(wr[d], Mr[d], t);
        s2 = fmaf(wr[c], t, s2);
    }
    const double invN = 1.0 / (double)NPIX;
    double cbo = (double)cb[tid];
    double mu = (double)s1 * invN + cbo;
    double ey2 = (double)s2 * invN + 2.0 * cbo * ((double)s1 * invN) + cbo * cbo;
    double var = ey2 - mu * mu;
    double A = (double)bg[tid] / sqrt(var + 1e-5);
    Aout[tid] = (float)A;
    Bout[tid] = (float)((double)bb[tid] + A * (cbo - mu));
}

// ---------------------------------------------------------------------------
// Fused 1x1 conv + BN apply via MFMA. Block = (b,w): D[96 h][256 o].
// ---------------------------------------------------------------------------
__global__ __launch_bounds__(512, 2)
void conv_bn_kernel(const unsigned short* __restrict__ hh, const float* __restrict__ cw,
                    const float* __restrict__ Aarr, const float* __restrict__ Barr,
                    float* __restrict__ out)
{
    __shared__ alignas(16) unsigned char UsB[96 * 128];    // bf16 U, swizzled
    __shared__ alignas(16) unsigned char WtB[256 * 128];   // bf16 conv W, swizzled

    const int tid = threadIdx.x;
    const int b = blockIdx.x / 96, w = blockIdx.x % 96;

    for (int i4 = tid; i4 < 4096; i4 += 512) {
        int wrow = i4 >> 4, k4 = i4 & 15;
        float4 v = *(const float4*)(cw + (size_t)wrow * 64 + k4 * 4);
        ushort4 p; p.x = f2bf(v.x); p.y = f2bf(v.y); p.z = f2bf(v.z); p.w = f2bf(v.w);
        *(ushort4*)(WtB + wrow * 128 + ((k4 * 8) ^ ((wrow & 7) << 4))) = p;
    }
    for (int i = tid; i < 1536; i += 512) {
        int row = i >> 4, k4 = i & 15;   // row = h
        ushort4 p = *(const ushort4*)(hh + (((size_t)b * 96 + row) * 96 + w) * 64 + k4 * 4);
        *(ushort4*)(UsB + row * 128 + ((k4 * 8) ^ ((row & 7) << 4))) = p;
    }
    __syncthreads();

    const int wv = tid >> 6, lane = tid & 63;
    const int mbase = (wv >> 2) * 48, nbase = (wv & 3) * 64;
    const int lrow = lane & 15, lk = (lane >> 4) * 8;

    f32x4 acc[3][4];
#pragma unroll
    for (int m = 0; m < 3; ++m)
#pragma unroll
        for (int n = 0; n < 4; ++n)
            acc[m][n] = (f32x4){0.f, 0.f, 0.f, 0.f};

#pragma unroll
    for (int ks = 0; ks < 2; ++ks) {
        const int kb = (ks * 32 + lk) * 2;
        bf16x8 am[3], bn[4];
#pragma unroll
        for (int m = 0; m < 3; ++m) {
            int row = mbase + m * 16 + lrow;
            am[m] = *(const bf16x8*)(UsB + row * 128 + (kb ^ ((row & 7) << 4)));
        }
#pragma unroll
        for (int n = 0; n < 4; ++n) {
            int o = nbase + n * 16 + lrow;
            bn[n] = *(const bf16x8*)(WtB + o * 128 + (kb ^ ((o & 7) << 4)));
        }
#pragma unroll
        for (int m = 0; m < 3; ++m)
#pragma unroll
            for (int n = 0; n < 4; ++n)
                acc[m][n] = __builtin_amdgcn_mfma_f32_16x16x32_bf16(am[m], bn[n], acc[m][n], 0, 0, 0);
    }

    const int hbase0 = (lane >> 4) * 4;
#pragma unroll
    for (int n = 0; n < 4; ++n) {
        const int o = nbase + n * 16 + lrow;
        const float Ao = Aarr[o], Bo = Barr[o];
        float* obase = out + (((size_t)b * 256 + o) * 96 + w) * 96;
#pragma unroll
        for (int m = 0; m < 3; ++m) {
            const int h0 = mbase + m * 16 + hbase0;
            float4 res;
            res.x = fmaf(Ao, acc[m][n][0], Bo);
            res.y = fmaf(Ao, acc[m][n][1], Bo);
            res.z = fmaf(Ao, acc[m][n][2], Bo);
            res.w = fmaf(Ao, acc[m][n][3], Bo);
            *(float4*)(obase + h0) = res;
        }
    }
}

extern "C" void kernel_launch(void* const* d_in, const int* in_sizes, int n_in,
                              void* d_out, int out_size, void* d_ws, size_t ws_size,
                              hipStream_t stream)
{
    const float* x       = (const float*)d_in[0];
    const float* v_wih_f = (const float*)d_in[1];
    const float* v_whh_f = (const float*)d_in[2];
    const float* v_bih_f = (const float*)d_in[3];
    const float* v_bhh_f = (const float*)d_in[4];
    const float* v_wih_b = (const float*)d_in[5];
    const float* v_whh_b = (const float*)d_in[6];
    const float* v_bih_b = (const float*)d_in[7];
    const float* v_bhh_b = (const float*)d_in[8];
    const float* h_wih_f = (const float*)d_in[9];
    const float* h_whh_f = (const float*)d_in[10];
    const float* h_bih_f = (const float*)d_in[11];
    const float* h_bhh_f = (const float*)d_in[12];
    const float* h_wih_b = (const float*)d_in[13];
    const float* h_whh_b = (const float*)d_in[14];
    const float* h_bih_b = (const float*)d_in[15];
    const float* h_bhh_b = (const float*)d_in[16];
    const float* conv_w  = (const float*)d_in[17];
    const float* conv_b  = (const float*)d_in[18];
    const float* bn_g    = (const float*)d_in[19];
    const float* bn_b    = (const float*)d_in[20];
    float* out = (float*)d_out;

    // d_out (302 MB) doubles as scratch before conv_bn rewrites all of it:
    //   bytes [0, 151 MB): xg buffer (bf16, gate-major [chain][256 o][96 t])
    //   tail 37.7 MB: v (bf16 [B,H,W,64]) — vertical LSTM output
    const size_t v_elems = (size_t)Bn * Hn * Wn * 64;   // 18,874,368 bf16
    unsigned short* v_buf = (unsigned short*)(out + (size_t)out_size) - v_elems;
    unsigned short* xgbuf = (unsigned short*)d_out;      // 150,994,944 bytes

    // workspace layout (~40 MB)
    unsigned short* hh = (unsigned short*)d_ws;                       // bf16 [B,H,W,64]
    char* wsb = (char*)d_ws;
    float* part = (float*)(wsb + 37748736);                           // 128 x 4160 f32
    float* M    = (float*)(wsb + 37748736 + 2129920);                 // 4160 f32
    float* Aarr = M + 4160;
    float* Barr = Aarr + 256;

    // vertical pass
    xg_kernel<1><<<3072, 512, 0, stream>>>(x, v_wih_f, v_bih_f, v_bhh_f,
                                           v_wih_b, v_bih_b, v_bhh_b, xgbuf);
    lstm_rec<1><<<1536, 256, 0, stream>>>(xgbuf, v_whh_f, v_whh_b, v_buf);
    // horizontal pass
    xg_kernel<0><<<3072, 512, 0, stream>>>(v_buf, h_wih_f, h_bih_f, h_bhh_f,
                                           h_wih_b, h_bih_b, h_bhh_b, xgbuf);
    lstm_rec<0><<<1536, 256, 0, stream>>>(xgbuf, h_whh_f, h_whh_b, hh);
    // conv + BN (affine-folded via Gram-matrix stats)
    gram_partial<<<GRAM_BLOCKS, 256, 0, stream>>>(hh, part);
    gram_reduce<<<17, 256, 0, stream>>>(part, M);
    stats_kernel<<<1, 256, 0, stream>>>(M, conv_w, conv_b, bn_g, bn_b, Aarr, Barr);
    conv_bn_kernel<<<3072, 512, 0, stream>>>(hh, conv_w, Aarr, Barr, out);
}

// Round 7
// 833.222 us; speedup vs baseline: 1.1199x; 1.1199x over previous
//
#include <hip/hip_runtime.h>
#include <stdint.h>

#define DI __device__ __forceinline__

constexpr int Bn = 32, Cc = 64, Wn = 96, Hn = 96, Ln = 32, NG = 128, OUTC = 256;
constexpr int SEQ = 96;
constexpr long long NPIX = (long long)Bn * Wn * Hn;   // 294912
constexpr int GRAM_BLOCKS = 128;
constexpr int PIX_PER_BLOCK = (int)(NPIX / GRAM_BLOCKS); // 2304

typedef __attribute__((ext_vector_type(8))) short bf16x8;
typedef __attribute__((ext_vector_type(4))) float f32x4;

DI float tanhf_(float x) { return 1.0f - 2.0f / (__expf(2.0f * x) + 1.0f); } // NaN-free both tails
DI float bf2f(unsigned short u) { return __uint_as_float(((unsigned)u) << 16); }
DI unsigned short f2bf(float f) {
    unsigned u = __float_as_uint(f);
    u += 0x7FFFu + ((u >> 16) & 1u);   // RNE
    return (unsigned short)(u >> 16);
}

// ---------------------------------------------------------------------------
// Input-projection GEMM via MFMA. One block per chain (b,q); A = 96x64 tile.
// OUTPUT LAYOUT (R6 change): xg[chain][chunk c][gate o][u], t = 8c+u.
// R5 [t][o]: coalesced but 256B/wave outstanding -> latency-bound (600 GB/s).
// R6 [o][t]: deep per-lane streams but 192B lane stride -> 64 lines/wave
// touched, 4x FETCH amplification (606MB vs 151MB), 291us. Chunk-interleave
// gives BOTH: one wave load = 64 lanes x 16B = 1KB contiguous, 8 steps deep.
// TRANSPOSE=1: input x f32 [B,C,W,H], q=w, t=h (transpose in staging).
// TRANSPOSE=0: input v bf16 [B,H,W,64], q=h, t=w (contiguous slab).
// ---------------------------------------------------------------------------
template<int TRANSPOSE>
__global__ __launch_bounds__(512, 4)
void xg_kernel(const void* __restrict__ in_,
               const float* __restrict__ wih_f, const float* __restrict__ bih_f,
               const float* __restrict__ bhh_f,
               const float* __restrict__ wih_b, const float* __restrict__ bih_b,
               const float* __restrict__ bhh_b,
               unsigned short* __restrict__ xg)
{
    __shared__ alignas(16) unsigned char AsB[96 * 128];    // bf16 A, swizzled
    __shared__ alignas(16) unsigned char WtB[256 * 128];   // bf16 W^T, swizzled
    __shared__ float biasS[256];

    const int tid = threadIdx.x;
    const int b = blockIdx.x / 96, q = blockIdx.x % 96;

    if (tid < 256) {
        int o = tid, g = o & 127;
        biasS[o] = (o < 128) ? (bih_f[g] + bhh_f[g]) : (bih_b[g] + bhh_b[g]);
    }
    for (int i4 = tid; i4 < 4096; i4 += 512) {
        int wrow = i4 >> 4, k4 = i4 & 15;
        const float* wsrc = (wrow < 128 ? wih_f : wih_b) + (size_t)(wrow & 127) * 64 + k4 * 4;
        float4 v = *(const float4*)wsrc;
        ushort4 p; p.x = f2bf(v.x); p.y = f2bf(v.y); p.z = f2bf(v.z); p.w = f2bf(v.w);
        *(ushort4*)(WtB + wrow * 128 + ((k4 * 8) ^ ((wrow & 7) << 4))) = p;
    }
    if (TRANSPOSE) {
        const float* in = (const float*)in_;
        for (int i = tid; i < 1536; i += 512) {
            int c = i / 24, h4 = i - c * 24;
            float4 v = *(const float4*)(in + (((size_t)b * 64 + c) * 96 + q) * 96 + 4 * h4);
            int r0 = 4 * h4;
            float vv[4] = {v.x, v.y, v.z, v.w};
#pragma unroll
            for (int j = 0; j < 4; ++j) {
                int row = r0 + j;
                *(unsigned short*)(AsB + row * 128 + ((c * 2) ^ ((row & 7) << 4))) = f2bf(vv[j]);
            }
        }
    } else {
        const unsigned short* src = (const unsigned short*)in_ + (size_t)blockIdx.x * 6144;
        for (int i8 = tid; i8 < 768; i8 += 512) {
            int row = i8 >> 3, k8 = i8 & 7;
            bf16x8 p = *(const bf16x8*)(src + (size_t)i8 * 8);
            *(bf16x8*)(AsB + row * 128 + ((k8 * 16) ^ ((row & 7) << 4))) = p;
        }
    }
    __syncthreads();

    const int wv = tid >> 6, lane = tid & 63;
    const int mbase = (wv >> 2) * 48;
    const int nbase = (wv & 3) * 64;
    const int lrow = lane & 15, lk = (lane >> 4) * 8;

    f32x4 acc[3][4];
#pragma unroll
    for (int m = 0; m < 3; ++m)
#pragma unroll
        for (int n = 0; n < 4; ++n)
            acc[m][n] = (f32x4){0.f, 0.f, 0.f, 0.f};

#pragma unroll
    for (int ks = 0; ks < 2; ++ks) {
        const int kb = (ks * 32 + lk) * 2;
        bf16x8 am[3], bn[4];
#pragma unroll
        for (int m = 0; m < 3; ++m) {
            int row = mbase + m * 16 + lrow;
            am[m] = *(const bf16x8*)(AsB + row * 128 + (kb ^ ((row & 7) << 4)));
        }
#pragma unroll
        for (int n = 0; n < 4; ++n) {
            int o = nbase + n * 16 + lrow;
            bn[n] = *(const bf16x8*)(WtB + o * 128 + (kb ^ ((o & 7) << 4)));
        }
#pragma unroll
        for (int m = 0; m < 3; ++m)
#pragma unroll
            for (int n = 0; n < 4; ++n)
                acc[m][n] = __builtin_amdgcn_mfma_f32_16x16x32_bf16(am[m], bn[n], acc[m][n], 0, 0, 0);
    }

    // write [chunk][o][u]: lane's 4 consecutive t sit inside one chunk (u0=0|4)
    unsigned short* ob = xg + (size_t)blockIdx.x * (96 * 256);
#pragma unroll
    for (int n = 0; n < 4; ++n) {
        const int o = nbase + n * 16 + lrow;
        const float bv = biasS[o];
#pragma unroll
        for (int m = 0; m < 3; ++m) {
            const int t0 = mbase + m * 16 + (lane >> 4) * 4;
            const int chunk = t0 >> 3, u0 = t0 & 7;
            ushort4 p;
            p.x = f2bf(acc[m][n][0] + bv);
            p.y = f2bf(acc[m][n][1] + bv);
            p.z = f2bf(acc[m][n][2] + bv);
            p.w = f2bf(acc[m][n][3] + bv);
            *(ushort4*)(ob + (size_t)chunk * 2048 + o * 8 + u0) = p;
        }
    }
}

// ---------------------------------------------------------------------------
// Recurrent-only BiLSTM, one WAVE per (chain, dir), barrier-free.
// Lane owns gates gA=lane (i|f), gB=64+lane (g|o). Chunk-interleaved xg:
// per chunk the wave issues two 1KB-contiguous 16B/lane loads (8 steps of
// data), 2-chunk prefetch pipeline hides HBM latency under ~16 steps of
// compute. Output bf16 both passes.
// ---------------------------------------------------------------------------
#define LSTM_STEP(EL, TE)                                                      \
    {                                                                          \
        const float xA = bf2f((unsigned short)fA[EL]);                         \
        const float xB = bf2f((unsigned short)fB[EL]);                         \
        float aA0 = xA, aA1 = 0.f, aB0 = xB, aB1 = 0.f;                        \
        _Pragma("unroll")                                                      \
        for (int j = 0; j < 32; j += 2) {                                      \
            const float h0 = __shfl(hval, j);                                  \
            const float h1 = __shfl(hval, j + 1);                              \
            aA0 = fmaf(whA[j], h0, aA0);                                       \
            aB0 = fmaf(whB[j], h0, aB0);                                       \
            aA1 = fmaf(whA[j + 1], h1, aA1);                                   \
            aB1 = fmaf(whB[j + 1], h1, aB1);                                   \
        }                                                                      \
        const float aA = aA0 + aA1, aB = aB0 + aB1;                            \
        const float actA = 1.f / (1.f + __expf(-aA));                          \
        const float eB = 1.f / (1.f + __expf(-scB * aB));                      \
        const float actB = fmaf(eB, maB, baB);                                 \
        const float fo = __shfl_xor(actA, 32);                                 \
        const float oo = __shfl_xor(actB, 32);                                 \
        cst = fmaf(fo, cst, actA * actB);                                      \
        const float hnew = oo * tanhf_(cst);                                   \
        hval = hnew;                                                           \
        if (lane < 32) {                                                       \
            const size_t oidx = VERT                                           \
                ? ((((size_t)b * 96 + (TE)) * 96 + q) * 64 + dir * 32 + lane)  \
                : ((((size_t)b * 96 + q) * 96 + (TE)) * 64 + dir * 32 + lane); \
            outU[oidx] = f2bf(hnew);                                           \
        }                                                                      \
    }

template<int VERT>
__global__ __launch_bounds__(256, 4)
void lstm_rec(const unsigned short* __restrict__ xg,
              const float* __restrict__ whh_f, const float* __restrict__ whh_b,
              unsigned short* __restrict__ outU)
{
    const int tid = threadIdx.x;
    const int wv = tid >> 6, lane = tid & 63;
    const int unit = blockIdx.x * 4 + wv;      // [0, 6144)
    const int chain = unit >> 1, dir = unit & 1;
    const int b = chain / 96, q = chain % 96;

    const float* whh = dir ? whh_b : whh_f;
    float whA[32], whB[32];
    {
        const float4* pa = (const float4*)(whh + (size_t)lane * 32);
        const float4* pb = (const float4*)(whh + (size_t)(lane + 64) * 32);
#pragma unroll
        for (int k = 0; k < 8; ++k) {
            float4 a = pa[k], v = pb[k];
            whA[4 * k + 0] = a.x; whA[4 * k + 1] = a.y; whA[4 * k + 2] = a.z; whA[4 * k + 3] = a.w;
            whB[4 * k + 0] = v.x; whB[4 * k + 1] = v.y; whB[4 * k + 2] = v.z; whB[4 * k + 3] = v.w;
        }
    }
    // B-gate activation: lanes<32 = g (tanh = 2*sigm(2x)-1), >=32 = o (sigm)
    const bool istB = (lane < 32);
    const float scB = istB ? 2.f : 1.f, maB = istB ? 2.f : 1.f, baB = istB ? -1.f : 0.f;

    // chunk-interleaved: chunk c at ubase + c*2048; lane's A chunk = 16B,
    // wave = 1KB contiguous; B stream at +512 elems.
    const unsigned short* ubase = xg + (size_t)chain * 24576 + (size_t)(dir * 128 + lane) * 8;
#define LOAD_A(cc) (*(const bf16x8*)(ubase + (size_t)(cc) * 2048))
#define LOAD_B(cc) (*(const bf16x8*)(ubase + (size_t)(cc) * 2048 + 512))

    bf16x8 curA = LOAD_A(dir ? 11 : 0), curB = LOAD_B(dir ? 11 : 0);
    bf16x8 nxtA = LOAD_A(dir ? 10 : 1), nxtB = LOAD_B(dir ? 10 : 1);

    float hval = 0.f, cst = 0.f;

    for (int c = 0; c < 12; ++c) {
        const bf16x8 fA = curA, fB = curB;
        bf16x8 farA = curA, farB = curB;
        if (c < 10) {
            const int cc = dir ? 9 - c : c + 2;
            farA = LOAD_A(cc); farB = LOAD_B(cc);
        }
        const int tbase = (dir ? 11 - c : c) * 8;
        if (dir == 0) {
#pragma unroll
            for (int u = 0; u < 8; ++u) LSTM_STEP(u, tbase + u)
        } else {
#pragma unroll
            for (int u = 0; u < 8; ++u) LSTM_STEP(7 - u, tbase + 7 - u)
        }
        curA = nxtA; curB = nxtB;
        nxtA = farA; nxtB = farB;
    }
#undef LOAD_A
#undef LOAD_B
}

// ---------------------------------------------------------------------------
// Partial Gram (64x64) + channel-sum (64) of hh over this block's pixel chunk.
// ---------------------------------------------------------------------------
__global__ __launch_bounds__(256)
void gram_partial(const unsigned short* __restrict__ hh, float* __restrict__ part)
{
    __shared__ float xs[64][64];
    __shared__ float red[4160];
    const int tid = threadIdx.x;
    for (int e = tid; e < 4160; e += 256) red[e] = 0.0f;
    const int lane = tid & 63, wv = tid >> 6;
    const int li = lane >> 3, lj = lane & 7;
    float acc[8][8]; float macc[8];
#pragma unroll
    for (int i = 0; i < 8; ++i) {
        macc[i] = 0.f;
#pragma unroll
        for (int j = 0; j < 8; ++j) acc[i][j] = 0.f;
    }
    const size_t pix0 = (size_t)blockIdx.x * PIX_PER_BLOCK;
    for (int tile = 0; tile < PIX_PER_BLOCK / 64; ++tile) {
        __syncthreads();
        const unsigned short* src = hh + (pix0 + tile * 64) * 64;
#pragma unroll
        for (int r = 0; r < 4; ++r) {
            int idx4 = tid + 256 * r;
            ushort4 v = ((const ushort4*)src)[idx4];
            int fi = idx4 * 4; int px = fi >> 6; int c = fi & 63;
            xs[px][c] = bf2f(v.x); xs[px][c + 1] = bf2f(v.y);
            xs[px][c + 2] = bf2f(v.z); xs[px][c + 3] = bf2f(v.w);
        }
        __syncthreads();
        for (int p = wv * 16; p < wv * 16 + 16; ++p) {
            float4 ra = *(const float4*)&xs[p][8 * li];
            float4 rb = *(const float4*)&xs[p][8 * li + 4];
            float4 ca = *(const float4*)&xs[p][8 * lj];
            float4 cb = *(const float4*)&xs[p][8 * lj + 4];
            float r[8] = {ra.x, ra.y, ra.z, ra.w, rb.x, rb.y, rb.z, rb.w};
            float cl[8] = {ca.x, ca.y, ca.z, ca.w, cb.x, cb.y, cb.z, cb.w};
#pragma unroll
            for (int i = 0; i < 8; ++i) {
#pragma unroll
                for (int j = 0; j < 8; ++j) acc[i][j] = fmaf(r[i], cl[j], acc[i][j]);
            }
            if (lj == 0) {
#pragma unroll
                for (int i = 0; i < 8; ++i) macc[i] += r[i];
            }
        }
    }
    __syncthreads();
#pragma unroll
    for (int i = 0; i < 8; ++i)
#pragma unroll
        for (int j = 0; j < 8; ++j)
            atomicAdd(&red[(8 * li + i) * 64 + 8 * lj + j], acc[i][j]);
    if (lj == 0)
        for (int i = 0; i < 8; ++i) atomicAdd(&red[4096 + 8 * li + i], macc[i]);
    __syncthreads();
    for (int e = tid; e < 4160; e += 256) part[(size_t)blockIdx.x * 4160 + e] = red[e];
}

__global__ void gram_reduce(const float* __restrict__ part, float* __restrict__ M)
{
    int e = blockIdx.x * 256 + threadIdx.x;
    if (e >= 4160) return;
    double s = 0.0;
    for (int p = 0; p < GRAM_BLOCKS; ++p) s += (double)part[(size_t)p * 4160 + e];
    M[e] = (float)s;
}

// Per-output-channel affine coefficients A,B such that out = A*(w_o . u) + B.
// Weights rounded through bf16 so A/B match the bf16-MFMA conv exactly.
__global__ __launch_bounds__(256)
void stats_kernel(const float* __restrict__ M, const float* __restrict__ cw,
                  const float* __restrict__ cb, const float* __restrict__ bg,
                  const float* __restrict__ bb,
                  float* __restrict__ Aout, float* __restrict__ Bout)
{
    __shared__ float Ml[4160];
    const int tid = threadIdx.x;
    for (int e = tid; e < 4160; e += 256) Ml[e] = M[e];
    __syncthreads();
    float wr[64];
#pragma unroll
    for (int c = 0; c < 64; ++c) wr[c] = bf2f(f2bf(cw[tid * 64 + c]));
    float s1 = 0.f;
#pragma unroll
    for (int c = 0; c < 64; ++c) s1 = fmaf(wr[c], Ml[4096 + c], s1);
    float s2 = 0.f;
    for (int c = 0; c < 64; ++c) {
        const float* Mr = &Ml[c * 64];
        float t = 0.f;
#pragma unroll
        for (int d = 0; d < 64; ++d) t = fmaf(wr[d], Mr[d], t);
        s2 = fmaf(wr[c], t, s2);
    }
    const double invN = 1.0 / (double)NPIX;
    double cbo = (double)cb[tid];
    double mu = (double)s1 * invN + cbo;
    double ey2 = (double)s2 * invN + 2.0 * cbo * ((double)s1 * invN) + cbo * cbo;
    double var = ey2 - mu * mu;
    double A = (double)bg[tid] / sqrt(var + 1e-5);
    Aout[tid] = (float)A;
    Bout[tid] = (float)((double)bb[tid] + A * (cbo - mu));
}

// ---------------------------------------------------------------------------
// Fused 1x1 conv + BN apply via MFMA. Block = (b,w): D[96 h][256 o].
// ---------------------------------------------------------------------------
__global__ __launch_bounds__(512, 2)
void conv_bn_kernel(const unsigned short* __restrict__ hh, const float* __restrict__ cw,
                    const float* __restrict__ Aarr, const float* __restrict__ Barr,
                    float* __restrict__ out)
{
    __shared__ alignas(16) unsigned char UsB[96 * 128];    // bf16 U, swizzled
    __shared__ alignas(16) unsigned char WtB[256 * 128];   // bf16 conv W, swizzled

    const int tid = threadIdx.x;
    const int b = blockIdx.x / 96, w = blockIdx.x % 96;

    for (int i4 = tid; i4 < 4096; i4 += 512) {
        int wrow = i4 >> 4, k4 = i4 & 15;
        float4 v = *(const float4*)(cw + (size_t)wrow * 64 + k4 * 4);
        ushort4 p; p.x = f2bf(v.x); p.y = f2bf(v.y); p.z = f2bf(v.z); p.w = f2bf(v.w);
        *(ushort4*)(WtB + wrow * 128 + ((k4 * 8) ^ ((wrow & 7) << 4))) = p;
    }
    for (int i = tid; i < 1536; i += 512) {
        int row = i >> 4, k4 = i & 15;   // row = h
        ushort4 p = *(const ushort4*)(hh + (((size_t)b * 96 + row) * 96 + w) * 64 + k4 * 4);
        *(ushort4*)(UsB + row * 128 + ((k4 * 8) ^ ((row & 7) << 4))) = p;
    }
    __syncthreads();

    const int wv = tid >> 6, lane = tid & 63;
    const int mbase = (wv >> 2) * 48, nbase = (wv & 3) * 64;
    const int lrow = lane & 15, lk = (lane >> 4) * 8;

    f32x4 acc[3][4];
#pragma unroll
    for (int m = 0; m < 3; ++m)
#pragma unroll
        for (int n = 0; n < 4; ++n)
            acc[m][n] = (f32x4){0.f, 0.f, 0.f, 0.f};

#pragma unroll
    for (int ks = 0; ks < 2; ++ks) {
        const int kb = (ks * 32 + lk) * 2;
        bf16x8 am[3], bn[4];
#pragma unroll
        for (int m = 0; m < 3; ++m) {
            int row = mbase + m * 16 + lrow;
            am[m] = *(const bf16x8*)(UsB + row * 128 + (kb ^ ((row & 7) << 4)));
        }
#pragma unroll
        for (int n = 0; n < 4; ++n) {
            int o = nbase + n * 16 + lrow;
            bn[n] = *(const bf16x8*)(WtB + o * 128 + (kb ^ ((o & 7) << 4)));
        }
#pragma unroll
        for (int m = 0; m < 3; ++m)
#pragma unroll
            for (int n = 0; n < 4; ++n)
                acc[m][n] = __builtin_amdgcn_mfma_f32_16x16x32_bf16(am[m], bn[n], acc[m][n], 0, 0, 0);
    }

    const int hbase0 = (lane >> 4) * 4;
#pragma unroll
    for (int n = 0; n < 4; ++n) {
        const int o = nbase + n * 16 + lrow;
        const float Ao = Aarr[o], Bo = Barr[o];
        float* obase = out + (((size_t)b * 256 + o) * 96 + w) * 96;
#pragma unroll
        for (int m = 0; m < 3; ++m) {
            const int h0 = mbase + m * 16 + hbase0;
            float4 res;
            res.x = fmaf(Ao, acc[m][n][0], Bo);
            res.y = fmaf(Ao, acc[m][n][1], Bo);
            res.z = fmaf(Ao, acc[m][n][2], Bo);
            res.w = fmaf(Ao, acc[m][n][3], Bo);
            *(float4*)(obase + h0) = res;
        }
    }
}

extern "C" void kernel_launch(void* const* d_in, const int* in_sizes, int n_in,
                              void* d_out, int out_size, void* d_ws, size_t ws_size,
                              hipStream_t stream)
{
    const float* x       = (const float*)d_in[0];
    const float* v_wih_f = (const float*)d_in[1];
    const float* v_whh_f = (const float*)d_in[2];
    const float* v_bih_f = (const float*)d_in[3];
    const float* v_bhh_f = (const float*)d_in[4];
    const float* v_wih_b = (const float*)d_in[5];
    const float* v_whh_b = (const float*)d_in[6];
    const float* v_bih_b = (const float*)d_in[7];
    const float* v_bhh_b = (const float*)d_in[8];
    const float* h_wih_f = (const float*)d_in[9];
    const float* h_whh_f = (const float*)d_in[10];
    const float* h_bih_f = (const float*)d_in[11];
    const float* h_bhh_f = (const float*)d_in[12];
    const float* h_wih_b = (const float*)d_in[13];
    const float* h_whh_b = (const float*)d_in[14];
    const float* h_bih_b = (const float*)d_in[15];
    const float* h_bhh_b = (const float*)d_in[16];
    const float* conv_w  = (const float*)d_in[17];
    const float* conv_b  = (const float*)d_in[18];
    const float* bn_g    = (const float*)d_in[19];
    const float* bn_b    = (const float*)d_in[20];
    float* out = (float*)d_out;

    // d_out (302 MB) doubles as scratch before conv_bn rewrites all of it:
    //   bytes [0, 151 MB): xg buffer (bf16, [chain][chunk][gate][u])
    //   tail 37.7 MB: v (bf16 [B,H,W,64]) — vertical LSTM output
    const size_t v_elems = (size_t)Bn * Hn * Wn * 64;   // 18,874,368 bf16
    unsigned short* v_buf = (unsigned short*)(out + (size_t)out_size) - v_elems;
    unsigned short* xgbuf = (unsigned short*)d_out;      // 150,994,944 bytes

    // workspace layout (~40 MB)
    unsigned short* hh = (unsigned short*)d_ws;                       // bf16 [B,H,W,64]
    char* wsb = (char*)d_ws;
    float* part = (float*)(wsb + 37748736);                           // 128 x 4160 f32
    float* M    = (float*)(wsb + 37748736 + 2129920);                 // 4160 f32
    float* Aarr = M + 4160;
    float* Barr = Aarr + 256;

    // vertical pass
    xg_kernel<1><<<3072, 512, 0, stream>>>(x, v_wih_f, v_bih_f, v_bhh_f,
                                           v_wih_b, v_bih_b, v_bhh_b, xgbuf);
    lstm_rec<1><<<1536, 256, 0, stream>>>(xgbuf, v_whh_f, v_whh_b, v_buf);
    // horizontal pass
    xg_kernel<0><<<3072, 512, 0, stream>>>(v_buf, h_wih_f, h_bih_f, h_bhh_f,
                                           h_wih_b, h_bih_b, h_bhh_b, xgbuf);
    lstm_rec<0><<<1536, 256, 0, stream>>>(xgbuf, h_whh_f, h_whh_b, hh);
    // conv + BN (affine-folded via Gram-matrix stats)
    gram_partial<<<GRAM_BLOCKS, 256, 0, stream>>>(hh, part);
    gram_reduce<<<17, 256, 0, stream>>>(part, M);
    stats_kernel<<<1, 256, 0, stream>>>(M, conv_w, conv_b, bn_g, bn_b, Aarr, Barr);
    conv_bn_kernel<<<3072, 512, 0, stream>>>(hh, conv_w, Aarr, Barr, out);
}

// Round 8
// 588.695 us; speedup vs baseline: 1.5850x; 1.4154x over previous
//
#include <hip/hip_runtime.h>
#include <stdint.h>

#define DI __device__ __forceinline__

constexpr int Bn = 32, Cc = 64, Wn = 96, Hn = 96, Ln = 32, NG = 128, OUTC = 256;
constexpr int SEQ = 96;
constexpr long long NPIX = (long long)Bn * Wn * Hn;   // 294912
constexpr int GRAM_BLOCKS = 128;
constexpr int PIX_PER_BLOCK = (int)(NPIX / GRAM_BLOCKS); // 2304

typedef __attribute__((ext_vector_type(8))) short bf16x8;
typedef __attribute__((ext_vector_type(4))) float f32x4;

DI float tanhf_(float x) { return 1.0f - 2.0f / (__expf(2.0f * x) + 1.0f); } // NaN-free both tails
DI float bf2f(unsigned short u) { return __uint_as_float(((unsigned)u) << 16); }
DI unsigned short f2bf(float f) {
    unsigned u = __float_as_uint(f);
    u += 0x7FFFu + ((u >> 16) & 1u);   // RNE
    return (unsigned short)(u >> 16);
}

// ---------------------------------------------------------------------------
// Input-projection GEMM via MFMA. One block per chain (b,q); A = 96x64 tile.
// xg layout: [chain][chunk c][gate o][u], t = 8c+u  (chunk-interleaved, R6).
// ---------------------------------------------------------------------------
template<int TRANSPOSE>
__global__ __launch_bounds__(512, 4)
void xg_kernel(const void* __restrict__ in_,
               const float* __restrict__ wih_f, const float* __restrict__ bih_f,
               const float* __restrict__ bhh_f,
               const float* __restrict__ wih_b, const float* __restrict__ bih_b,
               const float* __restrict__ bhh_b,
               unsigned short* __restrict__ xg)
{
    __shared__ alignas(16) unsigned char AsB[96 * 128];    // bf16 A, swizzled
    __shared__ alignas(16) unsigned char WtB[256 * 128];   // bf16 W^T, swizzled
    __shared__ float biasS[256];

    const int tid = threadIdx.x;
    const int b = blockIdx.x / 96, q = blockIdx.x % 96;

    if (tid < 256) {
        int o = tid, g = o & 127;
        biasS[o] = (o < 128) ? (bih_f[g] + bhh_f[g]) : (bih_b[g] + bhh_b[g]);
    }
    for (int i4 = tid; i4 < 4096; i4 += 512) {
        int wrow = i4 >> 4, k4 = i4 & 15;
        const float* wsrc = (wrow < 128 ? wih_f : wih_b) + (size_t)(wrow & 127) * 64 + k4 * 4;
        float4 v = *(const float4*)wsrc;
        ushort4 p; p.x = f2bf(v.x); p.y = f2bf(v.y); p.z = f2bf(v.z); p.w = f2bf(v.w);
        *(ushort4*)(WtB + wrow * 128 + ((k4 * 8) ^ ((wrow & 7) << 4))) = p;
    }
    if (TRANSPOSE) {
        const float* in = (const float*)in_;
        for (int i = tid; i < 1536; i += 512) {
            int c = i / 24, h4 = i - c * 24;
            float4 v = *(const float4*)(in + (((size_t)b * 64 + c) * 96 + q) * 96 + 4 * h4);
            int r0 = 4 * h4;
            float vv[4] = {v.x, v.y, v.z, v.w};
#pragma unroll
            for (int j = 0; j < 4; ++j) {
                int row = r0 + j;
                *(unsigned short*)(AsB + row * 128 + ((c * 2) ^ ((row & 7) << 4))) = f2bf(vv[j]);
            }
        }
    } else {
        const unsigned short* src = (const unsigned short*)in_ + (size_t)blockIdx.x * 6144;
        for (int i8 = tid; i8 < 768; i8 += 512) {
            int row = i8 >> 3, k8 = i8 & 7;
            bf16x8 p = *(const bf16x8*)(src + (size_t)i8 * 8);
            *(bf16x8*)(AsB + row * 128 + ((k8 * 16) ^ ((row & 7) << 4))) = p;
        }
    }
    __syncthreads();

    const int wv = tid >> 6, lane = tid & 63;
    const int mbase = (wv >> 2) * 48;
    const int nbase = (wv & 3) * 64;
    const int lrow = lane & 15, lk = (lane >> 4) * 8;

    f32x4 acc[3][4];
#pragma unroll
    for (int m = 0; m < 3; ++m)
#pragma unroll
        for (int n = 0; n < 4; ++n)
            acc[m][n] = (f32x4){0.f, 0.f, 0.f, 0.f};

#pragma unroll
    for (int ks = 0; ks < 2; ++ks) {
        const int kb = (ks * 32 + lk) * 2;
        bf16x8 am[3], bn[4];
#pragma unroll
        for (int m = 0; m < 3; ++m) {
            int row = mbase + m * 16 + lrow;
            am[m] = *(const bf16x8*)(AsB + row * 128 + (kb ^ ((row & 7) << 4)));
        }
#pragma unroll
        for (int n = 0; n < 4; ++n) {
            int o = nbase + n * 16 + lrow;
            bn[n] = *(const bf16x8*)(WtB + o * 128 + (kb ^ ((o & 7) << 4)));
        }
#pragma unroll
        for (int m = 0; m < 3; ++m)
#pragma unroll
            for (int n = 0; n < 4; ++n)
                acc[m][n] = __builtin_amdgcn_mfma_f32_16x16x32_bf16(am[m], bn[n], acc[m][n], 0, 0, 0);
    }

    // write [chunk][o][u]: lane's 4 consecutive t sit inside one chunk (u0=0|4)
    unsigned short* ob = xg + (size_t)blockIdx.x * (96 * 256);
#pragma unroll
    for (int n = 0; n < 4; ++n) {
        const int o = nbase + n * 16 + lrow;
        const float bv = biasS[o];
#pragma unroll
        for (int m = 0; m < 3; ++m) {
            const int t0 = mbase + m * 16 + (lane >> 4) * 4;
            const int chunk = t0 >> 3, u0 = t0 & 7;
            ushort4 p;
            p.x = f2bf(acc[m][n][0] + bv);
            p.y = f2bf(acc[m][n][1] + bv);
            p.z = f2bf(acc[m][n][2] + bv);
            p.w = f2bf(acc[m][n][3] + bv);
            *(ushort4*)(ob + (size_t)chunk * 2048 + o * 8 + u0) = p;
        }
    }
}

// ---------------------------------------------------------------------------
// Recurrent BiLSTM via per-step MFMA over 16 batched chains (R8 rewrite).
// R7 evidence: shfl-based matvec was latency-chain bound (256us, VALUBusy 54%,
// HBM 10%). Here: block = 16 chains x 1 dir, 256 thr = 4 waves; per step
// G[128][16] = Whh[128x32] @ H[32x16] as 2 MFMAs/wave (wave w = gate type w
// -> wave-uniform activation). H in dbuf LDS [n][k] bf16 stride 80B (16B
// aligned, bank-optimal b128). Gates cross waves via padded LDS gbuf.
// xg stays in REGISTERS: 8 x bf16x8 per lane per 8-step chunk, double-banked,
// statically indexed; loads are 16B/lane from the chunk-interleaved layout.
// 2 barriers/step; critical path ~300cyc/step vs ~2000 before.
// ---------------------------------------------------------------------------
DI void load_chunk(bf16x8* d, const unsigned short* base, int cc) {
    const unsigned short* p = base + (size_t)cc * 2048;
#pragma unroll
    for (int a = 0; a < 2; ++a)
#pragma unroll
        for (int r = 0; r < 4; ++r)
            d[a * 4 + r] = *(const bf16x8*)(p + a * 128 + r * 8);
}

#define RSTEP(U)                                                                  \
  {                                                                               \
    const int te = cc * 8 + (U);                                                  \
    bf16x8 hfrag = *(const bf16x8*)(hbufB[cur] + n_ * 80 + rg * 16);              \
    f32x4 zz = (f32x4){0.f, 0.f, 0.f, 0.f};                                       \
    f32x4 ac0 = __builtin_amdgcn_mfma_f32_16x16x32_bf16(af0, hfrag, zz, 0, 0, 0); \
    f32x4 ac1 = __builtin_amdgcn_mfma_f32_16x16x32_bf16(af1, hfrag, zz, 0, 0, 0); \
    _Pragma("unroll")                                                             \
    for (int r = 0; r < 4; ++r) {                                                 \
      const float p0 = ac0[r] + bf2f((unsigned short)xc[r][U]);                   \
      const float p1 = ac1[r] + bf2f((unsigned short)xc[4 + r][U]);               \
      const float e0 = 1.f / (1.f + __expf(-scW * p0));                           \
      const float e1 = 1.f / (1.f + __expf(-scW * p1));                           \
      gbuf[wv][rg * 4 + r][n_]      = fmaf(e0, maW, baW);                         \
      gbuf[wv][16 + rg * 4 + r][n_] = fmaf(e1, maW, baW);                         \
    }                                                                             \
    __syncthreads();                                                              \
    {                                                                             \
      const float gi0 = gbuf[0][l0][n0], gf0 = gbuf[1][l0][n0];                   \
      const float gg0 = gbuf[2][l0][n0], go0 = gbuf[3][l0][n0];                   \
      const float gi1 = gbuf[0][l1][n0], gf1 = gbuf[1][l1][n0];                   \
      const float gg1 = gbuf[2][l1][n0], go1 = gbuf[3][l1][n0];                   \
      c0 = fmaf(gf0, c0, gi0 * gg0);                                              \
      c1 = fmaf(gf1, c1, gi1 * gg1);                                              \
      const float h0 = go0 * tanhf_(c0);                                          \
      const float h1 = go1 * tanhf_(c1);                                          \
      *(unsigned short*)(hbufB[cur ^ 1] + n0 * 80 + l0 * 2) = f2bf(h0);           \
      *(unsigned short*)(hbufB[cur ^ 1] + n0 * 80 + l1 * 2) = f2bf(h1);           \
      const size_t obx = VERT                                                     \
        ? ((((size_t)b * 96 + te) * 96 + (q0 + n0)) * 64 + dir * 32)              \
        : ((((size_t)b * 96 + (q0 + n0)) * 96 + te) * 64 + dir * 32);             \
      outU[obx + l0] = f2bf(h0);                                                  \
      outU[obx + l1] = f2bf(h1);                                                  \
    }                                                                             \
    __syncthreads();                                                              \
    cur ^= 1;                                                                     \
  }

template<int VERT>
__global__ __launch_bounds__(256, 2)
void lstm_rec(const unsigned short* __restrict__ xg,
              const float* __restrict__ whh_f, const float* __restrict__ whh_b,
              unsigned short* __restrict__ outU)
{
    __shared__ alignas(16) unsigned char hbufB[2][16 * 80];   // bf16 H^T [n][k], stride 80B
    __shared__ float gbuf[4][32][17];                          // activated gates, padded

    const int tid = threadIdx.x;
    const int wv = tid >> 6, lane = tid & 63;
    const int dir = blockIdx.x & 1, grp = blockIdx.x >> 1;    // 192 groups x 2 dirs
    const int chain0 = grp * 16;
    const int b = chain0 / 96, q0 = chain0 % 96;

    const int n_ = lane & 15, rg = lane >> 4;
    const int n0 = tid & 15, l0 = tid >> 4, l1 = l0 + 16;

    // A-fragments: Whh rows (gate type = wv), 2 M-tiles; bf16
    const float* whh = dir ? whh_b : whh_f;
    bf16x8 af0, af1;
    {
        const float* s0 = whh + (size_t)(wv * 32 + n_) * 32 + rg * 8;
        const float* s1 = whh + (size_t)(wv * 32 + 16 + n_) * 32 + rg * 8;
        float4 a0 = *(const float4*)s0, a1 = *(const float4*)(s0 + 4);
        float4 b0 = *(const float4*)s1, b1 = *(const float4*)(s1 + 4);
        af0[0]=f2bf(a0.x); af0[1]=f2bf(a0.y); af0[2]=f2bf(a0.z); af0[3]=f2bf(a0.w);
        af0[4]=f2bf(a1.x); af0[5]=f2bf(a1.y); af0[6]=f2bf(a1.z); af0[7]=f2bf(a1.w);
        af1[0]=f2bf(b0.x); af1[1]=f2bf(b0.y); af1[2]=f2bf(b0.z); af1[3]=f2bf(b0.w);
        af1[4]=f2bf(b1.x); af1[5]=f2bf(b1.y); af1[6]=f2bf(b1.z); af1[7]=f2bf(b1.w);
    }
    // wave-uniform activation constants (wave 2 = g-gate = tanh)
    const float scW = (wv == 2) ? 2.f : 1.f;
    const float maW = (wv == 2) ? 2.f : 1.f;
    const float baW = (wv == 2) ? -1.f : 0.f;

    // per-lane xg base (chunk-interleaved layout, elements)
    const unsigned short* base = xg + (size_t)(chain0 + n_) * 24576 + dir * 1024
                                    + wv * 256 + rg * 32;

    // zero initial H
    for (int i = tid; i < 320; i += 256) ((float*)hbufB[0])[i] = 0.f;

    bf16x8 xc[8], xn[8];
    load_chunk(xc, base, dir ? 11 : 0);
    float c0 = 0.f, c1 = 0.f;
    int cur = 0;
    __syncthreads();

    for (int pos = 0; pos < 12; ++pos) {
        const int nxt = (pos + 1 < 12) ? pos + 1 : 11;
        load_chunk(xn, base, dir ? 11 - nxt : nxt);
        const int cc = dir ? 11 - pos : pos;
        if (!dir) {
            RSTEP(0) RSTEP(1) RSTEP(2) RSTEP(3) RSTEP(4) RSTEP(5) RSTEP(6) RSTEP(7)
        } else {
            RSTEP(7) RSTEP(6) RSTEP(5) RSTEP(4) RSTEP(3) RSTEP(2) RSTEP(1) RSTEP(0)
        }
#pragma unroll
        for (int j = 0; j < 8; ++j) xc[j] = xn[j];
    }
}

// ---------------------------------------------------------------------------
// Partial Gram (64x64) + channel-sum (64) of hh over this block's pixel chunk.
// ---------------------------------------------------------------------------
__global__ __launch_bounds__(256)
void gram_partial(const unsigned short* __restrict__ hh, float* __restrict__ part)
{
    __shared__ float xs[64][64];
    __shared__ float red[4160];
    const int tid = threadIdx.x;
    for (int e = tid; e < 4160; e += 256) red[e] = 0.0f;
    const int lane = tid & 63, wv = tid >> 6;
    const int li = lane >> 3, lj = lane & 7;
    float acc[8][8]; float macc[8];
#pragma unroll
    for (int i = 0; i < 8; ++i) {
        macc[i] = 0.f;
#pragma unroll
        for (int j = 0; j < 8; ++j) acc[i][j] = 0.f;
    }
    const size_t pix0 = (size_t)blockIdx.x * PIX_PER_BLOCK;
    for (int tile = 0; tile < PIX_PER_BLOCK / 64; ++tile) {
        __syncthreads();
        const unsigned short* src = hh + (pix0 + tile * 64) * 64;
#pragma unroll
        for (int r = 0; r < 4; ++r) {
            int idx4 = tid + 256 * r;
            ushort4 v = ((const ushort4*)src)[idx4];
            int fi = idx4 * 4; int px = fi >> 6; int c = fi & 63;
            xs[px][c] = bf2f(v.x); xs[px][c + 1] = bf2f(v.y);
            xs[px][c + 2] = bf2f(v.z); xs[px][c + 3] = bf2f(v.w);
        }
        __syncthreads();
        for (int p = wv * 16; p < wv * 16 + 16; ++p) {
            float4 ra = *(const float4*)&xs[p][8 * li];
            float4 rb = *(const float4*)&xs[p][8 * li + 4];
            float4 ca = *(const float4*)&xs[p][8 * lj];
            float4 cb = *(const float4*)&xs[p][8 * lj + 4];
            float r[8] = {ra.x, ra.y, ra.z, ra.w, rb.x, rb.y, rb.z, rb.w};
            float cl[8] = {ca.x, ca.y, ca.z, ca.w, cb.x, cb.y, cb.z, cb.w};
#pragma unroll
            for (int i = 0; i < 8; ++i) {
#pragma unroll
                for (int j = 0; j < 8; ++j) acc[i][j] = fmaf(r[i], cl[j], acc[i][j]);
            }
            if (lj == 0) {
#pragma unroll
                for (int i = 0; i < 8; ++i) macc[i] += r[i];
            }
        }
    }
    __syncthreads();
#pragma unroll
    for (int i = 0; i < 8; ++i)
#pragma unroll
        for (int j = 0; j < 8; ++j)
            atomicAdd(&red[(8 * li + i) * 64 + 8 * lj + j], acc[i][j]);
    if (lj == 0)
        for (int i = 0; i < 8; ++i) atomicAdd(&red[4096 + 8 * li + i], macc[i]);
    __syncthreads();
    for (int e = tid; e < 4160; e += 256) part[(size_t)blockIdx.x * 4160 + e] = red[e];
}

__global__ void gram_reduce(const float* __restrict__ part, float* __restrict__ M)
{
    int e = blockIdx.x * 256 + threadIdx.x;
    if (e >= 4160) return;
    double s = 0.0;
    for (int p = 0; p < GRAM_BLOCKS; ++p) s += (double)part[(size_t)p * 4160 + e];
    M[e] = (float)s;
}

// Per-output-channel affine coefficients A,B such that out = A*(w_o . u) + B.
// Weights rounded through bf16 so A/B match the bf16-MFMA conv exactly.
__global__ __launch_bounds__(256)
void stats_kernel(const float* __restrict__ M, const float* __restrict__ cw,
                  const float* __restrict__ cb, const float* __restrict__ bg,
                  const float* __restrict__ bb,
                  float* __restrict__ Aout, float* __restrict__ Bout)
{
    __shared__ float Ml[4160];
    const int tid = threadIdx.x;
    for (int e = tid; e < 4160; e += 256) Ml[e] = M[e];
    __syncthreads();
    float wr[64];
#pragma unroll
    for (int c = 0; c < 64; ++c) wr[c] = bf2f(f2bf(cw[tid * 64 + c]));
    float s1 = 0.f;
#pragma unroll
    for (int c = 0; c < 64; ++c) s1 = fmaf(wr[c], Ml[4096 + c], s1);
    float s2 = 0.f;
    for (int c = 0; c < 64; ++c) {
        const float* Mr = &Ml[c * 64];
        float t = 0.f;
#pragma unroll
        for (int d = 0; d < 64; ++d) t = fmaf(wr[d], Mr[d], t);
        s2 = fmaf(wr[c], t, s2);
    }
    const double invN = 1.0 / (double)NPIX;
    double cbo = (double)cb[tid];
    double mu = (double)s1 * invN + cbo;
    double ey2 = (double)s2 * invN + 2.0 * cbo * ((double)s1 * invN) + cbo * cbo;
    double var = ey2 - mu * mu;
    double A = (double)bg[tid] / sqrt(var + 1e-5);
    Aout[tid] = (float)A;
    Bout[tid] = (float)((double)bb[tid] + A * (cbo - mu));
}

// ---------------------------------------------------------------------------
// Fused 1x1 conv + BN apply via MFMA. Block = (b,w): D[96 h][256 o].
// ---------------------------------------------------------------------------
__global__ __launch_bounds__(512, 2)
void conv_bn_kernel(const unsigned short* __restrict__ hh, const float* __restrict__ cw,
                    const float* __restrict__ Aarr, const float* __restrict__ Barr,
                    float* __restrict__ out)
{
    __shared__ alignas(16) unsigned char UsB[96 * 128];    // bf16 U, swizzled
    __shared__ alignas(16) unsigned char WtB[256 * 128];   // bf16 conv W, swizzled

    const int tid = threadIdx.x;
    const int b = blockIdx.x / 96, w = blockIdx.x % 96;

    for (int i4 = tid; i4 < 4096; i4 += 512) {
        int wrow = i4 >> 4, k4 = i4 & 15;
        float4 v = *(const float4*)(cw + (size_t)wrow * 64 + k4 * 4);
        ushort4 p; p.x = f2bf(v.x); p.y = f2bf(v.y); p.z = f2bf(v.z); p.w = f2bf(v.w);
        *(ushort4*)(WtB + wrow * 128 + ((k4 * 8) ^ ((wrow & 7) << 4))) = p;
    }
    for (int i = tid; i < 1536; i += 512) {
        int row = i >> 4, k4 = i & 15;   // row = h
        ushort4 p = *(const ushort4*)(hh + (((size_t)b * 96 + row) * 96 + w) * 64 + k4 * 4);
        *(ushort4*)(UsB + row * 128 + ((k4 * 8) ^ ((row & 7) << 4))) = p;
    }
    __syncthreads();

    const int wv = tid >> 6, lane = tid & 63;
    const int mbase = (wv >> 2) * 48, nbase = (wv & 3) * 64;
    const int lrow = lane & 15, lk = (lane >> 4) * 8;

    f32x4 acc[3][4];
#pragma unroll
    for (int m = 0; m < 3; ++m)
#pragma unroll
        for (int n = 0; n < 4; ++n)
            acc[m][n] = (f32x4){0.f, 0.f, 0.f, 0.f};

#pragma unroll
    for (int ks = 0; ks < 2; ++ks) {
        const int kb = (ks * 32 + lk) * 2;
        bf16x8 am[3], bn[4];
#pragma unroll
        for (int m = 0; m < 3; ++m) {
            int row = mbase + m * 16 + lrow;
            am[m] = *(const bf16x8*)(UsB + row * 128 + (kb ^ ((row & 7) << 4)));
        }
#pragma unroll
        for (int n = 0; n < 4; ++n) {
            int o = nbase + n * 16 + lrow;
            bn[n] = *(const bf16x8*)(WtB + o * 128 + (kb ^ ((o & 7) << 4)));
        }
#pragma unroll
        for (int m = 0; m < 3; ++m)
#pragma unroll
            for (int n = 0; n < 4; ++n)
                acc[m][n] = __builtin_amdgcn_mfma_f32_16x16x32_bf16(am[m], bn[n], acc[m][n], 0, 0, 0);
    }

    const int hbase0 = (lane >> 4) * 4;
#pragma unroll
    for (int n = 0; n < 4; ++n) {
        const int o = nbase + n * 16 + lrow;
        const float Ao = Aarr[o], Bo = Barr[o];
        float* obase = out + (((size_t)b * 256 + o) * 96 + w) * 96;
#pragma unroll
        for (int m = 0; m < 3; ++m) {
            const int h0 = mbase + m * 16 + hbase0;
            float4 res;
            res.x = fmaf(Ao, acc[m][n][0], Bo);
            res.y = fmaf(Ao, acc[m][n][1], Bo);
            res.z = fmaf(Ao, acc[m][n][2], Bo);
            res.w = fmaf(Ao, acc[m][n][3], Bo);
            *(float4*)(obase + h0) = res;
        }
    }
}

extern "C" void kernel_launch(void* const* d_in, const int* in_sizes, int n_in,
                              void* d_out, int out_size, void* d_ws, size_t ws_size,
                              hipStream_t stream)
{
    const float* x       = (const float*)d_in[0];
    const float* v_wih_f = (const float*)d_in[1];
    const float* v_whh_f = (const float*)d_in[2];
    const float* v_bih_f = (const float*)d_in[3];
    const float* v_bhh_f = (const float*)d_in[4];
    const float* v_wih_b = (const float*)d_in[5];
    const float* v_whh_b = (const float*)d_in[6];
    const float* v_bih_b = (const float*)d_in[7];
    const float* v_bhh_b = (const float*)d_in[8];
    const float* h_wih_f = (const float*)d_in[9];
    const float* h_whh_f = (const float*)d_in[10];
    const float* h_bih_f = (const float*)d_in[11];
    const float* h_bhh_f = (const float*)d_in[12];
    const float* h_wih_b = (const float*)d_in[13];
    const float* h_whh_b = (const float*)d_in[14];
    const float* h_bih_b = (const float*)d_in[15];
    const float* h_bhh_b = (const float*)d_in[16];
    const float* conv_w  = (const float*)d_in[17];
    const float* conv_b  = (const float*)d_in[18];
    const float* bn_g    = (const float*)d_in[19];
    const float* bn_b    = (const float*)d_in[20];
    float* out = (float*)d_out;

    // d_out (302 MB) doubles as scratch before conv_bn rewrites all of it:
    //   bytes [0, 151 MB): xg buffer (bf16, [chain][chunk][gate][u])
    //   tail 37.7 MB: v (bf16 [B,H,W,64]) — vertical LSTM output
    const size_t v_elems = (size_t)Bn * Hn * Wn * 64;   // 18,874,368 bf16
    unsigned short* v_buf = (unsigned short*)(out + (size_t)out_size) - v_elems;
    unsigned short* xgbuf = (unsigned short*)d_out;      // 150,994,944 bytes

    // workspace layout (~40 MB)
    unsigned short* hh = (unsigned short*)d_ws;                       // bf16 [B,H,W,64]
    char* wsb = (char*)d_ws;
    float* part = (float*)(wsb + 37748736);                           // 128 x 4160 f32
    float* M    = (float*)(wsb + 37748736 + 2129920);                 // 4160 f32
    float* Aarr = M + 4160;
    float* Barr = Aarr + 256;

    // vertical pass
    xg_kernel<1><<<3072, 512, 0, stream>>>(x, v_wih_f, v_bih_f, v_bhh_f,
                                           v_wih_b, v_bih_b, v_bhh_b, xgbuf);
    lstm_rec<1><<<384, 256, 0, stream>>>(xgbuf, v_whh_f, v_whh_b, v_buf);
    // horizontal pass
    xg_kernel<0><<<3072, 512, 0, stream>>>(v_buf, h_wih_f, h_bih_f, h_bhh_f,
                                           h_wih_b, h_bih_b, h_bhh_b, xgbuf);
    lstm_rec<0><<<384, 256, 0, stream>>>(xgbuf, h_whh_f, h_whh_b, hh);
    // conv + BN (affine-folded via Gram-matrix stats)
    gram_partial<<<GRAM_BLOCKS, 256, 0, stream>>>(hh, part);
    gram_reduce<<<17, 256, 0, stream>>>(part, M);
    stats_kernel<<<1, 256, 0, stream>>>(M, conv_w, conv_b, bn_g, bn_b, Aarr, Barr);
    conv_bn_kernel<<<3072, 512, 0, stream>>>(hh, conv_w, Aarr, Barr, out);
}